// Round 3
// baseline (201.424 us; speedup 1.0000x reference)
//
#include <hip/hip_runtime.h>
#include <math.h>

// LocalGatedKL on MI355X (all fp32).
//  k_transw     : WtT[c][o], WsT[c][o] transposes (coalesced read, scattered write); seeds mnmx/acc
//  k_gemm_t     : t32 = Wt @ ft at 32x32 (1x1 conv commuted before bilinear resize),
//                 4-way channel split, scalar-path weights (s_load), pixel-major out [pix][64]
//  k_resize_norm: bilinear 32->64 (half-pixel+clamp == jax edge renorm), sum 4 partials,
//                 in-thread channel normalize -> tn [pix][64], channel mean -> tm
//  k_sobel      : 3x3 sobel on tm (zero pad), per-image min/max via uint atomics (m >= 0)
//  k_gemm_s     : sn = normalize(Ws @ fs3), scalar-path weights, pixel-major out
//  k_aff<0>     : 24-neighbor affinities of sn (reflect pad), log_softmax -> slogp
//  k_aff<1>     : same for tn + entropy/edge gating + KL + masked weighted reduce (double atomics)
//  k_final      : out = sum(w*kl) / (sum(w)+1e-6)
// Workspace (floats): t32p 4x524288 | tn 2M | sn 2M | tm 32K | mag 32K | WtT 32K | WsT 16K
//                     slogp reuses t32p region (dead after resize). Total ~25.6 MB.

#define WS_T32   0u
#define WS_TN    2097152u
#define WS_SN    4194304u
#define WS_TM    6291456u
#define WS_MAG   6324224u
#define WS_WTT   6356992u
#define WS_WST   6389760u
#define WS_MNMX  6406144u
#define WS_ACC   6406160u
#define WS_SLOGP 0u           // 786432 floats, reuses t32p region

static __device__ __forceinline__ int reflect_idx(int i, int n) {
  if (i < 0) i = -i;
  if (i >= n) i = 2 * n - 2 - i;
  return i;
}

// Transposes + accumulator seeding.
__global__ __launch_bounds__(256) void k_transw(const float* __restrict__ Wt,
                                                const float* __restrict__ Ws,
                                                float* __restrict__ WtT,
                                                float* __restrict__ WsT,
                                                unsigned int* __restrict__ mnmx,
                                                double* __restrict__ accg) {
  if (blockIdx.x == 0) {
    int t = threadIdx.x;
    if (t < 8) mnmx[t] = 0x7F800000u;          // +inf (uint order == float order for >= 0)
    else if (t < 16) mnmx[t] = 0u;             // 0.0f
    else if (t == 16) { accg[0] = 0.0; accg[1] = 0.0; }
  }
  int idx = blockIdx.x * 256 + threadIdx.x;    // 0..49151
  if (idx < 32768) {
    int o = idx >> 9, c = idx & 511;
    WtT[c * 64 + o] = Wt[idx];
  } else {
    int j = idx - 32768;
    int o = j >> 8, c = j & 255;
    WsT[c * 64 + o] = Ws[j];
  }
}

// t32[part][b*1024+pix][o] = Wt[o][cslice] @ ft[b][cslice][pix]. grid (128,4), 256 thr.
// Wave wv owns outputs wv*16..+15; weights via uniform (scalar) loads from WtT.
__global__ __launch_bounds__(256) void k_gemm_t(const float* __restrict__ ft,
                                                const float* __restrict__ WtT,
                                                float* __restrict__ t32p) {
  const int tid = threadIdx.x;
  const int wvu = __builtin_amdgcn_readfirstlane(tid >> 6);
  const int ln = tid & 63;
  const int p = blockIdx.x * 64 + ln;           // 0..8191
  const int b = p >> 10, pix = p & 1023;
  const int cbase = blockIdx.y * 128;
  float ac[16];
#pragma unroll
  for (int i = 0; i < 16; i++) ac[i] = 0.f;
  const float* ftb = ft + ((size_t)b * 512 + cbase) * 1024 + pix;
  const float* wp = WtT + (size_t)cbase * 64 + wvu * 16;
  for (int c = 0; c < 128; c += 4) {
    float v0 = ftb[(size_t)(c + 0) * 1024];
    float v1 = ftb[(size_t)(c + 1) * 1024];
    float v2 = ftb[(size_t)(c + 2) * 1024];
    float v3 = ftb[(size_t)(c + 3) * 1024];
#pragma unroll
    for (int o = 0; o < 16; o++)
      ac[o] += wp[(c + 0) * 64 + o] * v0 + wp[(c + 1) * 64 + o] * v1
             + wp[(c + 2) * 64 + o] * v2 + wp[(c + 3) * 64 + o] * v3;
  }
  float4* outp = (float4*)(t32p + (size_t)blockIdx.y * 524288
                           + ((size_t)b * 1024 + pix) * 64 + wvu * 16);
#pragma unroll
  for (int j = 0; j < 4; j++)
    outp[j] = make_float4(ac[4 * j], ac[4 * j + 1], ac[4 * j + 2], ac[4 * j + 3]);
}

// bilinear 32->64, sum 4 channel-split partials, in-thread normalize -> tn, mean -> tm.
__global__ __launch_bounds__(128) void k_resize_norm(const float* __restrict__ t32p,
                                                     float* __restrict__ tn,
                                                     float* __restrict__ tm) {
  const int p = blockIdx.x * 128 + threadIdx.x;   // 0..32767
  const int b = p >> 12, pix = p & 4095;
  const int y = pix >> 6, x = pix & 63;
  float fy = 0.5f * y - 0.25f, fx = 0.5f * x - 0.25f;
  int y0f = (int)floorf(fy), x0f = (int)floorf(fx);
  float wy = fy - (float)y0f, wx = fx - (float)x0f;
  int y1 = min(y0f + 1, 31), x1 = min(x0f + 1, 31);
  int y0 = max(y0f, 0), x0 = max(x0f, 0);
  const int ip[4] = {y0 * 32 + x0, y0 * 32 + x1, y1 * 32 + x0, y1 * 32 + x1};
  const float wg[4] = {(1.f - wy) * (1.f - wx), (1.f - wy) * wx, wy * (1.f - wx), wy * wx};
  float v[64];
#pragma unroll
  for (int i = 0; i < 64; i++) v[i] = 0.f;
#pragma unroll
  for (int q = 0; q < 4; q++) {
    const float* src = t32p + ((size_t)b * 1024 + ip[q]) * 64;
    float wq = wg[q];
#pragma unroll
    for (int part = 0; part < 4; part++) {
      const float4* s4 = (const float4*)(src + (size_t)part * 524288);
#pragma unroll
      for (int cg = 0; cg < 16; cg++) {
        float4 f = s4[cg];
        v[4 * cg + 0] += wq * f.x; v[4 * cg + 1] += wq * f.y;
        v[4 * cg + 2] += wq * f.z; v[4 * cg + 3] += wq * f.w;
      }
    }
  }
  float sum = 0.f, ssq = 0.f;
#pragma unroll
  for (int i = 0; i < 64; i++) { sum += v[i]; ssq += v[i] * v[i]; }
  float rn = 1.f / fmaxf(sqrtf(ssq), 1e-12f);
  float4* tnp = (float4*)(tn + ((size_t)b * 4096 + pix) * 64);
#pragma unroll
  for (int cg = 0; cg < 16; cg++)
    tnp[cg] = make_float4(v[4 * cg] * rn, v[4 * cg + 1] * rn, v[4 * cg + 2] * rn, v[4 * cg + 3] * rn);
  tm[p] = sum * (1.f / 64.f);
}

__global__ __launch_bounds__(128) void k_sobel(const float* __restrict__ tm,
                                               float* __restrict__ mag,
                                               unsigned int* __restrict__ mnmx) {
  const int p = blockIdx.x * 128 + threadIdx.x;
  const int b = p >> 12, pix = p & 4095;
  const int y = pix >> 6, x = pix & 63;
  const float* img = tm + (size_t)b * 4096;
  float v[3][3];
#pragma unroll
  for (int r = -1; r <= 1; r++)
#pragma unroll
    for (int c = -1; c <= 1; c++) {
      int yy = y + r, xx = x + c;
      v[r + 1][c + 1] = (yy >= 0 && yy < 64 && xx >= 0 && xx < 64) ? img[yy * 64 + xx] : 0.f;
    }
  float gx = (v[0][2] - v[0][0]) + 2.f * (v[1][2] - v[1][0]) + (v[2][2] - v[2][0]);
  float gy = (v[2][0] - v[0][0]) + 2.f * (v[2][1] - v[0][1]) + (v[2][2] - v[0][2]);
  float m = sqrtf(gx * gx + gy * gy);
  mag[p] = m;
  unsigned int mu = __float_as_uint(m);
  unsigned int mnu = mu, mxu = mu;
#pragma unroll
  for (int off = 32; off >= 1; off >>= 1) {
    mnu = min(mnu, __shfl_xor(mnu, off));
    mxu = max(mxu, __shfl_xor(mxu, off));
  }
  if ((threadIdx.x & 63) == 0) {
    atomicMin(&mnmx[b], mnu);
    atomicMax(&mnmx[8 + b], mxu);
  }
}

// sn[b*4096+pix][o] = normalize(Ws @ fs3). 512 blocks x 256 thr; scalar-path weights.
__global__ __launch_bounds__(256) void k_gemm_s(const float* __restrict__ fs3,
                                                const float* __restrict__ WsT,
                                                float* __restrict__ sn) {
  __shared__ float ssq_l[4][64];
  const int tid = threadIdx.x;
  const int wvu = __builtin_amdgcn_readfirstlane(tid >> 6);
  const int ln = tid & 63;
  const int p = blockIdx.x * 64 + ln;           // 0..32767
  const int b = p >> 12, pix = p & 4095;
  float ac[16];
#pragma unroll
  for (int i = 0; i < 16; i++) ac[i] = 0.f;
  const float* fb = fs3 + (size_t)b * 256 * 4096 + pix;
  const float* wp = WsT + wvu * 16;
  for (int c = 0; c < 256; c += 4) {
    float v0 = fb[(size_t)(c + 0) * 4096];
    float v1 = fb[(size_t)(c + 1) * 4096];
    float v2 = fb[(size_t)(c + 2) * 4096];
    float v3 = fb[(size_t)(c + 3) * 4096];
#pragma unroll
    for (int o = 0; o < 16; o++)
      ac[o] += wp[(c + 0) * 64 + o] * v0 + wp[(c + 1) * 64 + o] * v1
             + wp[(c + 2) * 64 + o] * v2 + wp[(c + 3) * 64 + o] * v3;
  }
  float ss = 0.f;
#pragma unroll
  for (int i = 0; i < 16; i++) ss += ac[i] * ac[i];
  ssq_l[wvu][ln] = ss;
  __syncthreads();
  float tot = ssq_l[0][ln] + ssq_l[1][ln] + ssq_l[2][ln] + ssq_l[3][ln];
  float rn = 1.f / fmaxf(sqrtf(tot), 1e-12f);
  float4* ob = (float4*)(sn + ((size_t)b * 4096 + pix) * 64 + wvu * 16);
#pragma unroll
  for (int j = 0; j < 4; j++)
    ob[j] = make_float4(ac[4 * j] * rn, ac[4 * j + 1] * rn, ac[4 * j + 2] * rn, ac[4 * j + 3] * rn);
}

// 24-neighbor affinity + log_softmax; 8x8 tile, 12x12 reflect halo, all 64 ch staged once.
// LDS [144 pos][68] with XOR swizzle (c ^= ((pos*17>>3)&3)<<2) -> <=2-way bank conflicts.
// Wave wv computes partial dots over ch [wv*16,+16); LDS reduce; wave 0 finishes.
template <int TPASS>
__global__ __launch_bounds__(256) void k_aff(const float* __restrict__ fn,
                                             float* __restrict__ slogp,
                                             const float* __restrict__ mag,
                                             const unsigned int* __restrict__ mnmx,
                                             double* __restrict__ accg) {
  __shared__ __align__(16) float fl[144 * 68];   // 39.2 KB
  const int tid = threadIdx.x;
  const int wvu = __builtin_amdgcn_readfirstlane(tid >> 6);
  const int ln = tid & 63;
  const int b = blockIdx.x >> 6, tl = blockIdx.x & 63;
  const int ty0 = (tl >> 3) * 8, tx0 = (tl & 7) * 8;
  const int ty = ln >> 3, tx = ln & 7;
#pragma unroll
  for (int i = 0; i < 9; i++) {                  // 2304 float4 / 256 thr
    int flat = i * 256 + tid;
    int pos = flat >> 4, cg = flat & 15;
    int hy = pos / 12, hx = pos - hy * 12;
    int gy2 = reflect_idx(ty0 + hy - 2, 64);
    int gx2 = reflect_idx(tx0 + hx - 2, 64);
    float4 f = *(const float4*)(fn + ((size_t)b * 4096 + gy2 * 64 + gx2) * 64 + cg * 4);
    int sw = (((pos * 17) >> 3) & 3) << 2;
    *(float4*)(&fl[pos * 68 + ((cg * 4) ^ sw)]) = f;
  }
  __syncthreads();
  const int base = ty * 12 + tx;
  const int cbase = wvu * 16;
  float4 cv[4];
  {
    int cp = base + 26;                          // center
    int cs = (((cp * 17) >> 3) & 3) << 2;
    const float* crow = &fl[cp * 68];
#pragma unroll
    for (int j = 0; j < 4; j++) cv[j] = *(const float4*)(crow + ((cbase + 4 * j) ^ cs));
  }
  float aff[24];
  {
    int n = 0;
#pragma unroll
    for (int dy = 0; dy < 5; dy++)
#pragma unroll
      for (int dx = 0; dx < 5; dx++) {
        if (dy == 2 && dx == 2) continue;
        int pp = base + dy * 12 + dx;
        int sw2 = (((pp * 17) >> 3) & 3) << 2;
        const float* rowp = &fl[pp * 68];
        float4 n0 = *(const float4*)(rowp + ((cbase + 0) ^ sw2));
        float4 n1 = *(const float4*)(rowp + ((cbase + 4) ^ sw2));
        float4 n2 = *(const float4*)(rowp + ((cbase + 8) ^ sw2));
        float4 n3 = *(const float4*)(rowp + ((cbase + 12) ^ sw2));
        aff[n] = cv[0].x * n0.x + cv[0].y * n0.y + cv[0].z * n0.z + cv[0].w * n0.w
               + cv[1].x * n1.x + cv[1].y * n1.y + cv[1].z * n1.z + cv[1].w * n1.w
               + cv[2].x * n2.x + cv[2].y * n2.y + cv[2].z * n2.z + cv[2].w * n2.w
               + cv[3].x * n3.x + cv[3].y * n3.y + cv[3].z * n3.z + cv[3].w * n3.w;
        n++;
      }
  }
  __syncthreads();
  float* r = fl;                                 // reduce buffer [256][25] = 6400 floats
#pragma unroll
  for (int n = 0; n < 24; n++) r[(wvu * 64 + ln) * 25 + n] = aff[n];
  __syncthreads();
  if (wvu != 0) return;
  float a[24];
#pragma unroll
  for (int n = 0; n < 24; n++)
    a[n] = r[ln * 25 + n] + r[(64 + ln) * 25 + n] + r[(128 + ln) * 25 + n] + r[(192 + ln) * 25 + n];
  float mxa = a[0];
#pragma unroll
  for (int n = 1; n < 24; n++) mxa = fmaxf(mxa, a[n]);
  float e[24]; float sum = 0.f;
#pragma unroll
  for (int n = 0; n < 24; n++) { e[n] = expf((a[n] - mxa) * 10.f); sum += e[n]; }
  float lse = logf(sum);
  const int gy = ty0 + ty, gx = tx0 + tx;
  const int gpix = b * 4096 + gy * 64 + gx;
  if (TPASS == 0) {
#pragma unroll
    for (int n = 0; n < 24; n++)
      slogp[(size_t)n * 32768 + gpix] = (a[n] - mxa) * 10.f - lse;
  } else {
    float rs = 1.f / sum;
    float ent = 0.f, kl = 0.f;
#pragma unroll
    for (int n = 0; n < 24; n++) {
      float tp = e[n] * rs;
      float tlp = (a[n] - mxa) * 10.f - lse;
      ent -= tp * tlp;
      kl += tp * (tlp - slogp[(size_t)n * 32768 + gpix]);
    }
    float wconf = 1.f - ent * (1.0f / 3.17805383034794580f);   // MAXH = log(24)
    wconf = fminf(fmaxf(wconf, 0.f), 1.f);
    float mnv = __uint_as_float(mnmx[b]);
    float mxv = __uint_as_float(mnmx[8 + b]);
    float wedge = (mag[gpix] - mnv) / (mxv - mnv + 1e-6f);
    float w = wconf * wconf * (1.f + wedge);
    if (gy < 2 || gy >= 62 || gx < 2 || gx >= 62) w = 0.f;
    double wkl = (double)(w * kl), wsum = (double)w;
#pragma unroll
    for (int off = 32; off >= 1; off >>= 1) {
      wkl  += __shfl_down(wkl, off);
      wsum += __shfl_down(wsum, off);
    }
    if (ln == 0) { atomicAdd(&accg[0], wkl); atomicAdd(&accg[1], wsum); }
  }
}

__global__ void k_final(const double* __restrict__ accg, float* __restrict__ out) {
  out[0] = (float)(accg[0] / (accg[1] + 1e-6));
}

extern "C" void kernel_launch(void* const* d_in, const int* in_sizes, int n_in,
                              void* d_out, int out_size, void* d_ws, size_t ws_size,
                              hipStream_t stream) {
  const float* fs3 = (const float*)d_in[0];
  const float* ft  = (const float*)d_in[1];
  const float* Ws  = (const float*)d_in[2];
  const float* Wt  = (const float*)d_in[3];
  float* out = (float*)d_out;
  float* w = (float*)d_ws;
  float* t32   = w + WS_T32;
  float* tn    = w + WS_TN;
  float* sn    = w + WS_SN;
  float* tm    = w + WS_TM;
  float* mag   = w + WS_MAG;
  float* WtT   = w + WS_WTT;
  float* WsT   = w + WS_WST;
  float* slogp = w + WS_SLOGP;                   // reuses t32 region
  unsigned int* mnmx = (unsigned int*)(w + WS_MNMX);
  double* acc = (double*)(w + WS_ACC);

  k_transw<<<192, 256, 0, stream>>>(Wt, Ws, WtT, WsT, mnmx, acc);
  k_gemm_t<<<dim3(128, 4), 256, 0, stream>>>(ft, WtT, t32);
  k_resize_norm<<<256, 128, 0, stream>>>(t32, tn, tm);
  k_sobel<<<256, 128, 0, stream>>>(tm, mag, mnmx);
  k_gemm_s<<<512, 256, 0, stream>>>(fs3, WsT, sn);
  k_aff<0><<<512, 256, 0, stream>>>(sn, slogp, nullptr, nullptr, nullptr);
  k_aff<1><<<512, 256, 0, stream>>>(tn, slogp, mag, mnmx, acc);
  k_final<<<1, 1, 0, stream>>>(acc, out);
}